// Round 4
// baseline (169.766 us; speedup 1.0000x reference)
//
#include <hip/hip_runtime.h>

// Problem: B=8192, L=128, O=512, K=8, H=20
#define B_TOT 8192
#define O_DIM 512
#define L_DIM 128
#define K_DIM 8
#define H_DIM 20

// Tiling: one o per wave-iter, 64 b per wave (lane = b).
// 256 threads (4 waves), G=16 o per block, 4 iters/wave.
// __launch_bounds__(256,4): allocator gets <=128 VGPR (R3's forced 8 waves/EU
// starved it to 20 VGPR -> spill/shuffle glue; occupancy proved non-binding).
#define TB 64          // b per block (= wavefront)
#define G  16          // o per block (4 waves x 4 iterations)
#define NW 4           // waves per block
#define NTH 256
#define XSTR 65        // xT stride in f16 units; gather reads conflict-free
#define NSTR 17        // noise tile stride (f32): odd => read conflict-free

typedef _Float16 h2 __attribute__((ext_vector_type(2)));

// tanh(x) = 1 - 2/(1+exp(2x)); saturates correctly at +/-inf.
__device__ __forceinline__ float fast_tanh(float x) {
    float e = __builtin_amdgcn_exp2f(x * 2.885390081777927f); // 2*log2(e)
    float r = __builtin_amdgcn_rcpf(1.0f + e);
    return 1.0f - 2.0f * r;
}

// f16x2 dot with f32 accumulate: v_dot2_f32_f16 (full rate => 2 FLOP/lane/cyc).
__device__ __forceinline__ float dot2(h2 a, h2 b, float c) {
#if __has_builtin(__builtin_amdgcn_fdot2)
    return __builtin_amdgcn_fdot2(a, b, c, false);
#else
    return fmaf((float)a[0], (float)b[0], fmaf((float)a[1], (float)b[1], c));
#endif
}

__device__ __forceinline__ h2 uh2(unsigned u) {
    union { unsigned u; h2 h; } c; c.u = u; return c.h;
}

// packed f32->f16x2 convert (v_cvt_pkrtz_f16_f32)
__device__ __forceinline__ h2 pkrtz(float a, float b) {
    auto t = __builtin_amdgcn_cvt_pkrtz(a, b);
    return __builtin_bit_cast(h2, t);
}

// round-nearest f16 pack (weights, one-time)
__device__ __forceinline__ unsigned pk_rn(float a, float b) {
    unsigned short ua = __builtin_bit_cast(unsigned short, (_Float16)a);
    unsigned short ub = __builtin_bit_cast(unsigned short, (_Float16)b);
    return (unsigned)ua | ((unsigned)ub << 16);
}

// Per-o packed weights; biases folded in as f16 pairs (dot2-only inner loops):
//  layer1 input pairs: xp[0..3]=(x,x), xp[4]=(1.0, noise)
//  layer2 input pairs: ap[0..9]=(a1,a1), ap[10]=(1.0, 0)
//  layer3 input pairs: same as layer2
struct __align__(16) PackedW {
    unsigned w1pk[5][H_DIM];     // [kp][h]; kp<4: (W1[2kp+1][h], W1[2kp+2][h]); kp=4: (b1[h], W1[0][h])
    unsigned w2pk[H_DIM][11];    // [g][hp]; hp<10: (W2[2hp][g], W2[2hp+1][g]); hp=10: (b2[g], 0)
    unsigned w3pk[11];           // hp<10: (W3[2hp], W3[2hp+1]); hp=10: (b3, 0)
    unsigned pad;                // -> 332 dwords = 1328 B (16B multiple)
};

__global__ __launch_bounds__(64) void pack_weights(
    const float* __restrict__ W1, const float* __restrict__ b1,
    const float* __restrict__ W2, const float* __restrict__ b2,
    const float* __restrict__ W3, const float* __restrict__ b3,
    PackedW* __restrict__ pw)
{
    const int o = blockIdx.x;
    const int t = threadIdx.x;
    PackedW* p = pw + o;
    const float* w1 = W1 + (size_t)o * (K_DIM + 1) * H_DIM;
    const float* w2 = W2 + (size_t)o * H_DIM * H_DIM;
    for (int i = t; i < 4 * H_DIM; i += 64) {
        int kp = i / H_DIM, h = i % H_DIM;
        p->w1pk[kp][h] = pk_rn(w1[(2 * kp + 1) * H_DIM + h],
                               w1[(2 * kp + 2) * H_DIM + h]);
    }
    if (t < H_DIM)
        p->w1pk[4][t] = pk_rn(b1[o * H_DIM + t], w1[t]);   // (b1, W1[noise])
    for (int i = t; i < H_DIM * 10; i += 64) {
        int g = i / 10, hp = i % 10;
        p->w2pk[g][hp] = pk_rn(w2[(2 * hp) * H_DIM + g],
                               w2[(2 * hp + 1) * H_DIM + g]);
    }
    if (t < H_DIM)
        p->w2pk[t][10] = pk_rn(b2[o * H_DIM + t], 0.f);    // (b2, 0)
    if (t < 10) p->w3pk[t] = pk_rn(W3[o * H_DIM + 2 * t], W3[o * H_DIM + 2 * t + 1]);
    if (t == 10) p->w3pk[10] = pk_rn(b3[o], 0.f);          // (b3, 0)
    if (t == 11) p->pad = 0u;
}

__global__ __launch_bounds__(NTH, 4) void medil_fused_f16(
    const float* __restrict__ x, const float* __restrict__ noise,
    const int* __restrict__ cause_idx, const PackedW* __restrict__ pw,
    float* __restrict__ out)
{
    __shared__ _Float16 xT[L_DIM * XSTR];   // 16640 B, transposed x tile [col][b], f16
    __shared__ float    nt[TB * NSTR];      //  4352 B, noise tile [b][ol]
    // total 20992 B

    const int tid = threadIdx.x;
    const int o0 = (blockIdx.x & 31) * G;        // 512/16 = 32 o-groups
    const int b0 = (blockIdx.x >> 5) * TB;       // 8192/64 = 128 b-tiles

    // ---- stage x tile transposed + converted to f16: xT[col][b_local] ----
    {
        const float4* xg = (const float4*)(x + (size_t)b0 * L_DIM);
        #pragma unroll
        for (int i = 0; i < 8; ++i) {
            int idx = tid + NTH * i;             // 0..2047
            int r = idx >> 5, c4 = idx & 31;     // row (b), col4 (coalesced global)
            float4 v = xg[r * 32 + c4];
            xT[(c4 * 4 + 0) * XSTR + r] = (_Float16)v.x;
            xT[(c4 * 4 + 1) * XSTR + r] = (_Float16)v.y;
            xT[(c4 * 4 + 2) * XSTR + r] = (_Float16)v.z;
            xT[(c4 * 4 + 3) * XSTR + r] = (_Float16)v.w;
        }
    }
    // ---- stage noise tile [64 b][16 o], coalesced float4 loads ----
    {
        int r = tid >> 2, c4 = tid & 3;
        float4 v = *(const float4*)(noise + (size_t)(b0 + r) * O_DIM + o0 + c4 * 4);
        nt[r * NSTR + c4 * 4 + 0] = v.x;
        nt[r * NSTR + c4 * 4 + 1] = v.y;
        nt[r * NSTR + c4 * 4 + 2] = v.z;
        nt[r * NSTR + c4 * 4 + 3] = v.w;
    }
    __syncthreads();

    const int lane = tid & 63;   // = b_local
    const int wv = tid >> 6;     // 0..3

    const h2 onep = uh2(0x00003C00u);   // (1.0h, 0.0h) — bias pair for layers 2/3

    #pragma unroll
    for (int it = 0; it < G / NW; ++it) {
        // wave-uniform o => all W/idx accesses become scalar loads
        const int ol = __builtin_amdgcn_readfirstlane(wv * (G / NW) + it);
        const int o  = o0 + ol;

        const PackedW* P = pw + o;
        const int* cip = cause_idx + (size_t)o * K_DIM;

        // gather: col wave-uniform, lanes consecutive f16 -> same/adjacent words, free
        _Float16 xi[K_DIM];
        #pragma unroll
        for (int k = 0; k < K_DIM; ++k)
            xi[k] = xT[cip[k] * XSTR + lane];
        h2 xp[5];
        #pragma unroll
        for (int kp = 0; kp < 4; ++kp) {
            h2 t; t[0] = xi[2 * kp]; t[1] = xi[2 * kp + 1];  // v_pack_b32_f16
            xp[kp] = t;
        }
        xp[4] = pkrtz(1.0f, nt[lane * NSTR + ol]);           // (1.0, noise)

        // ---- layer 1: a1 = tanh(inp @ W1 + b1), pure dot2, bias folded ----
        float a1[H_DIM];
        #pragma unroll
        for (int h = 0; h < H_DIM; ++h)
            a1[h] = dot2(xp[0], uh2(P->w1pk[0][h]), 0.0f);
        #pragma unroll
        for (int kp = 1; kp < 5; ++kp)
            #pragma unroll
            for (int h = 0; h < H_DIM; ++h)
                a1[h] = dot2(xp[kp], uh2(P->w1pk[kp][h]), a1[h]);
        #pragma unroll
        for (int h = 0; h < H_DIM; ++h) a1[h] = fast_tanh(a1[h]);

        // pack activations to f16 pairs (RTZ, |a1|<=1)
        h2 ap[10];
        #pragma unroll
        for (int hp = 0; hp < 10; ++hp)
            ap[hp] = pkrtz(a1[2 * hp], a1[2 * hp + 1]);

        // ---- layer 2: a2 = tanh(a1 @ W2 + b2), 11 dot2 per g, bias folded ----
        float a2[H_DIM];
        #pragma unroll
        for (int g = 0; g < H_DIM; ++g) {
            float acc = dot2(ap[0], uh2(P->w2pk[g][0]), 0.0f);
            #pragma unroll
            for (int hp = 1; hp < 10; ++hp)
                acc = dot2(ap[hp], uh2(P->w2pk[g][hp]), acc);
            a2[g] = dot2(onep, uh2(P->w2pk[g][10]), acc);
        }
        #pragma unroll
        for (int g = 0; g < H_DIM; ++g) a2[g] = fast_tanh(a2[g]);

        // ---- layer 3 + store (scatter; L2 merges: block covers full o-lines) ----
        h2 tp[10];
        #pragma unroll
        for (int hp = 0; hp < 10; ++hp)
            tp[hp] = pkrtz(a2[2 * hp], a2[2 * hp + 1]);
        float r = dot2(tp[0], uh2(P->w3pk[0]), 0.0f);
        #pragma unroll
        for (int hp = 1; hp < 10; ++hp)
            r = dot2(tp[hp], uh2(P->w3pk[hp]), r);
        r = dot2(onep, uh2(P->w3pk[10]), r);
        out[(size_t)(b0 + lane) * O_DIM + o] = r;
    }
}

// ---------------- legacy fp32 fallback (only if ws too small) ----------------
#define XSTRF 65
__global__ __launch_bounds__(NTH, 4) void medil_fused_legacy(
    const float* __restrict__ x, const float* __restrict__ noise,
    const int* __restrict__ cause_idx,
    const float* __restrict__ W1, const float* __restrict__ b1,
    const float* __restrict__ W2, const float* __restrict__ b2,
    const float* __restrict__ W3, const float* __restrict__ b3,
    float* __restrict__ out)
{
    __shared__ float xT[L_DIM * XSTRF];
    __shared__ float nt[TB * NSTR];

    const int tid = threadIdx.x;
    const int o0 = (blockIdx.x & 31) * G;
    const int b0 = (blockIdx.x >> 5) * TB;

    {
        const float4* xg = (const float4*)(x + (size_t)b0 * L_DIM);
        #pragma unroll
        for (int i = 0; i < 8; ++i) {
            int idx = tid + NTH * i;
            int r = idx >> 5, c4 = idx & 31;
            float4 v = xg[r * 32 + c4];
            xT[(c4 * 4 + 0) * XSTRF + r] = v.x;
            xT[(c4 * 4 + 1) * XSTRF + r] = v.y;
            xT[(c4 * 4 + 2) * XSTRF + r] = v.z;
            xT[(c4 * 4 + 3) * XSTRF + r] = v.w;
        }
    }
    {
        int r = tid >> 2, c4 = tid & 3;
        float4 v = *(const float4*)(noise + (size_t)(b0 + r) * O_DIM + o0 + c4 * 4);
        nt[r * NSTR + c4 * 4 + 0] = v.x;
        nt[r * NSTR + c4 * 4 + 1] = v.y;
        nt[r * NSTR + c4 * 4 + 2] = v.z;
        nt[r * NSTR + c4 * 4 + 3] = v.w;
    }
    __syncthreads();

    const int lane = tid & 63;
    const int wv = tid >> 6;

    #pragma unroll
    for (int it = 0; it < G / NW; ++it) {
        const int ol = __builtin_amdgcn_readfirstlane(wv * (G / NW) + it);
        const int o  = o0 + ol;

        const float* w1p = W1 + (size_t)o * (K_DIM + 1) * H_DIM;
        const float* b1p = b1 + (size_t)o * H_DIM;
        const float* w2p = W2 + (size_t)o * H_DIM * H_DIM;
        const float* b2p = b2 + (size_t)o * H_DIM;
        const float* w3p = W3 + (size_t)o * H_DIM;
        const int*   cip = cause_idx + (size_t)o * K_DIM;

        float xi[K_DIM];
        #pragma unroll
        for (int k = 0; k < K_DIM; ++k)
            xi[k] = xT[cip[k] * XSTRF + lane];
        float inp0 = nt[lane * NSTR + ol];

        float a1[H_DIM];
        #pragma unroll
        for (int h = 0; h < H_DIM; ++h)
            a1[h] = fmaf(inp0, w1p[h], b1p[h]);
        #pragma unroll
        for (int k = 0; k < K_DIM; ++k)
            #pragma unroll
            for (int h = 0; h < H_DIM; ++h)
                a1[h] = fmaf(xi[k], w1p[(k + 1) * H_DIM + h], a1[h]);
        #pragma unroll
        for (int h = 0; h < H_DIM; ++h) a1[h] = fast_tanh(a1[h]);

        float a2[H_DIM];
        #pragma unroll
        for (int g = 0; g < H_DIM; ++g) a2[g] = b2p[g];
        #pragma unroll
        for (int h = 0; h < H_DIM; ++h)
            #pragma unroll
            for (int g = 0; g < H_DIM; ++g)
                a2[g] = fmaf(a1[h], w2p[h * H_DIM + g], a2[g]);
        #pragma unroll
        for (int g = 0; g < H_DIM; ++g) a2[g] = fast_tanh(a2[g]);

        float r = b3[o];
        #pragma unroll
        for (int h = 0; h < H_DIM; ++h) r = fmaf(a2[h], w3p[h], r);
        out[(size_t)(b0 + lane) * O_DIM + o] = r;
    }
}

extern "C" void kernel_launch(void* const* d_in, const int* in_sizes, int n_in,
                              void* d_out, int out_size, void* d_ws, size_t ws_size,
                              hipStream_t stream) {
    const float* x         = (const float*)d_in[0];
    const float* noise     = (const float*)d_in[1];
    const int*   cause_idx = (const int*)d_in[2];
    const float* W1        = (const float*)d_in[3];
    const float* b1        = (const float*)d_in[4];
    const float* W2        = (const float*)d_in[5];
    const float* b2        = (const float*)d_in[6];
    const float* W3        = (const float*)d_in[7];
    const float* b3        = (const float*)d_in[8];
    float* out = (float*)d_out;

    dim3 grid((B_TOT / TB) * (O_DIM / G));   // 128 * 32 = 4096 blocks
    dim3 block(NTH);

    if (ws_size >= sizeof(PackedW) * O_DIM) {
        PackedW* pw = (PackedW*)d_ws;
        hipLaunchKernelGGL(pack_weights, dim3(O_DIM), dim3(64), 0, stream,
                           W1, b1, W2, b2, W3, b3, pw);
        hipLaunchKernelGGL(medil_fused_f16, grid, block, 0, stream,
                           x, noise, cause_idx, pw, out);
    } else {
        hipLaunchKernelGGL(medil_fused_legacy, grid, block, 0, stream,
                           x, noise, cause_idx, W1, b1, W2, b2, W3, b3, out);
    }
}

// Round 5
// 161.678 us; speedup vs baseline: 1.0500x; 1.0500x over previous
//
#include <hip/hip_runtime.h>

// Problem: B=8192, L=128, O=512, K=8, H=20
#define B_TOT 8192
#define O_DIM 512
#define L_DIM 128
#define K_DIM 8
#define H_DIM 20

// Tiling: one o per wave-iter, 64 b per wave (lane = b). R2 structure (90.2us),
// single change: tanh via LDS (val,delta) interp table -> trans-port cycles
// (exp2+rcp = ~32 port-cyc/tanh) replaced by ~14 VALU cyc + 1 ds_read_b64.
#define TB 64          // b per block (= wavefront)
#define G  16          // o per block (4 waves x 4 iterations)
#define NW 4           // waves per block
#define NTH 256
#define XSTR 65        // xT stride in f16 units; gather reads conflict-free
#define NSTR 17        // noise tile stride (f32): odd => read conflict-free

// tanh table: 512 entries on [-8,8), step 1/32, linear interp
#define TSC 32.0f
#define TOF 256.0f
#define TMAX 510.99f

typedef _Float16 h2 __attribute__((ext_vector_type(2)));

// tanh(x) = 1 - 2/(1+exp(2x)); used only for one-time table build.
__device__ __forceinline__ float slow_tanh(float x) {
    float e = __builtin_amdgcn_exp2f(x * 2.885390081777927f); // 2*log2(e)
    float r = __builtin_amdgcn_rcpf(1.0f + e);
    return 1.0f - 2.0f * r;
}

// f16x2 dot with f32 accumulate: v_dot2_f32_f16 (full rate => 2 FLOP/lane/cyc).
__device__ __forceinline__ float dot2(h2 a, h2 b, float c) {
#if __has_builtin(__builtin_amdgcn_fdot2)
    return __builtin_amdgcn_fdot2(a, b, c, false);
#else
    return fmaf((float)a[0], (float)b[0], fmaf((float)a[1], (float)b[1], c));
#endif
}

__device__ __forceinline__ h2 uh2(unsigned u) {
    union { unsigned u; h2 h; } c; c.u = u; return c.h;
}

// packed f32->f16x2 convert (v_cvt_pkrtz_f16_f32)
__device__ __forceinline__ h2 pkrtz(float a, float b) {
    auto t = __builtin_amdgcn_cvt_pkrtz(a, b);
    return __builtin_bit_cast(h2, t);
}

// round-nearest f16 pack (weights, one-time)
__device__ __forceinline__ unsigned pk_rn(float a, float b) {
    unsigned short ua = __builtin_bit_cast(unsigned short, (_Float16)a);
    unsigned short ub = __builtin_bit_cast(unsigned short, (_Float16)b);
    return (unsigned)ua | ((unsigned)ub << 16);
}

// Per-o packed weights (R2 layout), contiguous wave-uniform s_loads.
struct __align__(16) PackedW {
    float    b1[H_DIM];          // @0
    float    w1n[H_DIM];         // @80   W1[k=0][h] (noise column, kept f32)
    unsigned w1pk[4][H_DIM];     // @160  [kp][h] = f16x2(W1[2kp+1][h], W1[2kp+2][h])
    unsigned w2pk[H_DIM][10];    // @480  [g][hp] = f16x2(W2[2hp][g],  W2[2hp+1][g])
    float    b2[H_DIM];          // @1280
    unsigned w3pk[10];           // @1360 [hp] = f16x2(W3[2hp], W3[2hp+1])
    float    b3;                 // @1400
    float    pad;                // @1404 -> 1408 B total (16B multiple)
};

__global__ __launch_bounds__(64) void pack_weights(
    const float* __restrict__ W1, const float* __restrict__ b1,
    const float* __restrict__ W2, const float* __restrict__ b2,
    const float* __restrict__ W3, const float* __restrict__ b3,
    PackedW* __restrict__ pw)
{
    const int o = blockIdx.x;
    const int t = threadIdx.x;
    PackedW* p = pw + o;
    const float* w1 = W1 + (size_t)o * (K_DIM + 1) * H_DIM;
    const float* w2 = W2 + (size_t)o * H_DIM * H_DIM;
    if (t < H_DIM) {
        p->b1[t]  = b1[o * H_DIM + t];
        p->w1n[t] = w1[t];                      // k = 0 row
        p->b2[t]  = b2[o * H_DIM + t];
    }
    for (int i = t; i < 4 * H_DIM; i += 64) {
        int kp = i / H_DIM, h = i % H_DIM;
        p->w1pk[kp][h] = pk_rn(w1[(2 * kp + 1) * H_DIM + h],
                               w1[(2 * kp + 2) * H_DIM + h]);
    }
    for (int i = t; i < H_DIM * 10; i += 64) {
        int g = i / 10, hp = i % 10;
        p->w2pk[g][hp] = pk_rn(w2[(2 * hp) * H_DIM + g],
                               w2[(2 * hp + 1) * H_DIM + g]);
    }
    if (t < 10) p->w3pk[t] = pk_rn(W3[o * H_DIM + 2 * t], W3[o * H_DIM + 2 * t + 1]);
    if (t == 0) { p->b3 = b3[o]; p->pad = 0.f; }
}

__global__ __launch_bounds__(NTH, 4) void medil_fused_f16(
    const float* __restrict__ x, const float* __restrict__ noise,
    const int* __restrict__ cause_idx, const PackedW* __restrict__ pw,
    float* __restrict__ out)
{
    __shared__ _Float16 xT[L_DIM * XSTR];   // 16640 B, transposed x tile [col][b], f16
    __shared__ float    nt[TB * NSTR];      //  4352 B, noise tile [b][ol]
    __shared__ float2   tbl[512];           //  4096 B, tanh (val, delta) table
    // total 25088 B -> 6 blocks/CU -> 24 waves/CU

    const int tid = threadIdx.x;
    const int o0 = (blockIdx.x & 31) * G;        // 512/16 = 32 o-groups
    const int b0 = (blockIdx.x >> 5) * TB;       // 8192/64 = 128 b-tiles

    // ---- build tanh table: entry i covers x in [(i-256)/32, +1/32) ----
    {
        #pragma unroll
        for (int j = tid; j < 512; j += NTH) {
            float xx = (float)(j - 256) * (1.0f / TSC);
            float v0 = slow_tanh(xx);
            float v1 = slow_tanh(xx + 1.0f / TSC);
            tbl[j] = make_float2(v0, v1 - v0);
        }
    }
    // ---- stage x tile transposed + converted to f16: xT[col][b_local] ----
    {
        const float4* xg = (const float4*)(x + (size_t)b0 * L_DIM);
        #pragma unroll
        for (int i = 0; i < 8; ++i) {
            int idx = tid + NTH * i;             // 0..2047
            int r = idx >> 5, c4 = idx & 31;     // row (b), col4 (coalesced global)
            float4 v = xg[r * 32 + c4];
            xT[(c4 * 4 + 0) * XSTR + r] = (_Float16)v.x;
            xT[(c4 * 4 + 1) * XSTR + r] = (_Float16)v.y;
            xT[(c4 * 4 + 2) * XSTR + r] = (_Float16)v.z;
            xT[(c4 * 4 + 3) * XSTR + r] = (_Float16)v.w;
        }
    }
    // ---- stage noise tile [64 b][16 o], coalesced float4 loads ----
    {
        int r = tid >> 2, c4 = tid & 3;
        float4 v = *(const float4*)(noise + (size_t)(b0 + r) * O_DIM + o0 + c4 * 4);
        nt[r * NSTR + c4 * 4 + 0] = v.x;
        nt[r * NSTR + c4 * 4 + 1] = v.y;
        nt[r * NSTR + c4 * 4 + 2] = v.z;
        nt[r * NSTR + c4 * 4 + 3] = v.w;
    }
    __syncthreads();

    const int lane = tid & 63;   // = b_local
    const int wv = tid >> 6;     // 0..3

    // table-interp tanh: ~14 VALU port-cyc + 1 ds_read_b64 (vs 38 for exp+rcp)
    auto lut_tanh = [&](float v) -> float {
        float t = fmaf(v, TSC, TOF);
        t = fminf(fmaxf(t, 0.0f), TMAX);
        int i = (int)t;
        float f = __builtin_amdgcn_fractf(t);
        float2 e = tbl[i];
        return fmaf(f, e.y, e.x);
    };

    #pragma unroll
    for (int it = 0; it < G / NW; ++it) {
        // wave-uniform o => all W/idx accesses become scalar loads
        const int ol = __builtin_amdgcn_readfirstlane(wv * (G / NW) + it);
        const int o  = o0 + ol;

        const PackedW* P = pw + o;
        const int* cip = cause_idx + (size_t)o * K_DIM;

        // gather: col wave-uniform, lanes consecutive f16 -> conflict-free
        _Float16 xi[K_DIM];
        #pragma unroll
        for (int k = 0; k < K_DIM; ++k)
            xi[k] = xT[cip[k] * XSTR + lane];
        h2 xp[4];
        #pragma unroll
        for (int kp = 0; kp < 4; ++kp) {
            h2 t; t[0] = xi[2 * kp]; t[1] = xi[2 * kp + 1];  // v_pack_b32_f16
            xp[kp] = t;
        }
        float inp0 = nt[lane * NSTR + ol];

        // ---- layer 1: a1 = tanh(inp @ W1 + b1); noise column f32, rest dot2 ----
        float a1[H_DIM];
        #pragma unroll
        for (int h = 0; h < H_DIM; ++h)
            a1[h] = fmaf(inp0, P->w1n[h], P->b1[h]);
        #pragma unroll
        for (int kp = 0; kp < 4; ++kp)
            #pragma unroll
            for (int h = 0; h < H_DIM; ++h)
                a1[h] = dot2(xp[kp], uh2(P->w1pk[kp][h]), a1[h]);
        #pragma unroll
        for (int h = 0; h < H_DIM; ++h) a1[h] = lut_tanh(a1[h]);

        // pack activations to f16 pairs (RTZ, |a1|<=1)
        h2 ap[10];
        #pragma unroll
        for (int hp = 0; hp < 10; ++hp)
            ap[hp] = pkrtz(a1[2 * hp], a1[2 * hp + 1]);

        // ---- layer 2: a2 = tanh(a1 @ W2 + b2), 10 dot2 per g (f32 accumulate) ----
        float a2[H_DIM];
        #pragma unroll
        for (int g = 0; g < H_DIM; ++g) {
            float acc = P->b2[g];
            #pragma unroll
            for (int hp = 0; hp < 10; ++hp)
                acc = dot2(ap[hp], uh2(P->w2pk[g][hp]), acc);
            a2[g] = acc;
        }
        #pragma unroll
        for (int g = 0; g < H_DIM; ++g) a2[g] = lut_tanh(a2[g]);

        // ---- layer 3 + store (scatter; L2 merges: block covers full o-lines) ----
        h2 tp[10];
        #pragma unroll
        for (int hp = 0; hp < 10; ++hp)
            tp[hp] = pkrtz(a2[2 * hp], a2[2 * hp + 1]);
        float r = P->b3;
        #pragma unroll
        for (int hp = 0; hp < 10; ++hp)
            r = dot2(tp[hp], uh2(P->w3pk[hp]), r);
        out[(size_t)(b0 + lane) * O_DIM + o] = r;
    }
}

// ---------------- legacy fp32 fallback (only if ws too small) ----------------
#define XSTRF 65
__global__ __launch_bounds__(NTH, 4) void medil_fused_legacy(
    const float* __restrict__ x, const float* __restrict__ noise,
    const int* __restrict__ cause_idx,
    const float* __restrict__ W1, const float* __restrict__ b1,
    const float* __restrict__ W2, const float* __restrict__ b2,
    const float* __restrict__ W3, const float* __restrict__ b3,
    float* __restrict__ out)
{
    __shared__ float xT[L_DIM * XSTRF];
    __shared__ float nt[TB * NSTR];

    const int tid = threadIdx.x;
    const int o0 = (blockIdx.x & 31) * G;
    const int b0 = (blockIdx.x >> 5) * TB;

    {
        const float4* xg = (const float4*)(x + (size_t)b0 * L_DIM);
        #pragma unroll
        for (int i = 0; i < 8; ++i) {
            int idx = tid + NTH * i;
            int r = idx >> 5, c4 = idx & 31;
            float4 v = xg[r * 32 + c4];
            xT[(c4 * 4 + 0) * XSTRF + r] = v.x;
            xT[(c4 * 4 + 1) * XSTRF + r] = v.y;
            xT[(c4 * 4 + 2) * XSTRF + r] = v.z;
            xT[(c4 * 4 + 3) * XSTRF + r] = v.w;
        }
    }
    {
        int r = tid >> 2, c4 = tid & 3;
        float4 v = *(const float4*)(noise + (size_t)(b0 + r) * O_DIM + o0 + c4 * 4);
        nt[r * NSTR + c4 * 4 + 0] = v.x;
        nt[r * NSTR + c4 * 4 + 1] = v.y;
        nt[r * NSTR + c4 * 4 + 2] = v.z;
        nt[r * NSTR + c4 * 4 + 3] = v.w;
    }
    __syncthreads();

    const int lane = tid & 63;
    const int wv = tid >> 6;

    #pragma unroll
    for (int it = 0; it < G / NW; ++it) {
        const int ol = __builtin_amdgcn_readfirstlane(wv * (G / NW) + it);
        const int o  = o0 + ol;

        const float* w1p = W1 + (size_t)o * (K_DIM + 1) * H_DIM;
        const float* b1p = b1 + (size_t)o * H_DIM;
        const float* w2p = W2 + (size_t)o * H_DIM * H_DIM;
        const float* b2p = b2 + (size_t)o * H_DIM;
        const float* w3p = W3 + (size_t)o * H_DIM;
        const int*   cip = cause_idx + (size_t)o * K_DIM;

        float xi[K_DIM];
        #pragma unroll
        for (int k = 0; k < K_DIM; ++k)
            xi[k] = xT[cip[k] * XSTRF + lane];
        float inp0 = nt[lane * NSTR + ol];

        float a1[H_DIM];
        #pragma unroll
        for (int h = 0; h < H_DIM; ++h)
            a1[h] = fmaf(inp0, w1p[h], b1p[h]);
        #pragma unroll
        for (int k = 0; k < K_DIM; ++k)
            #pragma unroll
            for (int h = 0; h < H_DIM; ++h)
                a1[h] = fmaf(xi[k], w1p[(k + 1) * H_DIM + h], a1[h]);
        #pragma unroll
        for (int h = 0; h < H_DIM; ++h) a1[h] = slow_tanh(a1[h]);

        float a2[H_DIM];
        #pragma unroll
        for (int g = 0; g < H_DIM; ++g) a2[g] = b2p[g];
        #pragma unroll
        for (int h = 0; h < H_DIM; ++h)
            #pragma unroll
            for (int g = 0; g < H_DIM; ++g)
                a2[g] = fmaf(a1[h], w2p[h * H_DIM + g], a2[g]);
        #pragma unroll
        for (int g = 0; g < H_DIM; ++g) a2[g] = slow_tanh(a2[g]);

        float r = b3[o];
        #pragma unroll
        for (int h = 0; h < H_DIM; ++h) r = fmaf(a2[h], w3p[h], r);
        out[(size_t)(b0 + lane) * O_DIM + o] = r;
    }
}

extern "C" void kernel_launch(void* const* d_in, const int* in_sizes, int n_in,
                              void* d_out, int out_size, void* d_ws, size_t ws_size,
                              hipStream_t stream) {
    const float* x         = (const float*)d_in[0];
    const float* noise     = (const float*)d_in[1];
    const int*   cause_idx = (const int*)d_in[2];
    const float* W1        = (const float*)d_in[3];
    const float* b1        = (const float*)d_in[4];
    const float* W2        = (const float*)d_in[5];
    const float* b2        = (const float*)d_in[6];
    const float* W3        = (const float*)d_in[7];
    const float* b3        = (const float*)d_in[8];
    float* out = (float*)d_out;

    dim3 grid((B_TOT / TB) * (O_DIM / G));   // 128 * 32 = 4096 blocks
    dim3 block(NTH);

    if (ws_size >= sizeof(PackedW) * O_DIM) {
        PackedW* pw = (PackedW*)d_ws;
        hipLaunchKernelGGL(pack_weights, dim3(O_DIM), dim3(64), 0, stream,
                           W1, b1, W2, b2, W3, b3, pw);
        hipLaunchKernelGGL(medil_fused_f16, grid, block, 0, stream,
                           x, noise, cause_idx, pw, out);
    } else {
        hipLaunchKernelGGL(medil_fused_legacy, grid, block, 0, stream,
                           x, noise, cause_idx, W1, b1, W2, b2, W3, b3, out);
    }
}